// Round 3
// baseline (454.788 us; speedup 1.0000x reference)
//
#include <hip/hip_runtime.h>
#include <hip/hip_bf16.h>

#define N 8192
#define FIN 512
#define FOUT 64
#define ALPHA 0.2f

typedef __bf16 bf16x8 __attribute__((ext_vector_type(8)));
typedef float f32x4 __attribute__((ext_vector_type(4)));
typedef int i32x4 __attribute__((ext_vector_type(4)));

// ---- workspace layout (bytes) ----
// [0,64)            : Mkey (ordered-uint global max of f_dst)
// [64, 32832)       : lsum (N floats)
// [32832, 65600)    : f_src (N floats)
// [65600, 98368)    : f_dst (N floats)
// [98368, 163904)   : WtG  (bf16 [FOUT][FIN], W transposed)
// [163904, 1212480) : hT   (bf16 [FOUT][N], h transposed)

__device__ __forceinline__ unsigned enc_f(float x) {
    unsigned u = __float_as_uint(x);
    return (u & 0x80000000u) ? ~u : (u | 0x80000000u);
}
__device__ __forceinline__ float dec_f(unsigned u) {
    return (u & 0x80000000u) ? __uint_as_float(u & 0x7FFFFFFFu) : __uint_as_float(~u);
}

// ---------- k_wt: WtG[f][k] = bf16(W[k][f]) --------------------------------
__global__ __launch_bounds__(64) void k_wt(const float* __restrict__ W,
                                           __bf16* __restrict__ WtG) {
    const int g = blockIdx.x * 64 + threadIdx.x;  // 0..4095
    const int k = g >> 3;
    const int f0 = (g & 7) * 8;
    const float4 w0 = *(const float4*)(W + (size_t)k * FOUT + f0);
    const float4 w1 = *(const float4*)(W + (size_t)k * FOUT + f0 + 4);
    WtG[(size_t)(f0 + 0) * FIN + k] = (__bf16)w0.x;
    WtG[(size_t)(f0 + 1) * FIN + k] = (__bf16)w0.y;
    WtG[(size_t)(f0 + 2) * FIN + k] = (__bf16)w0.z;
    WtG[(size_t)(f0 + 3) * FIN + k] = (__bf16)w0.w;
    WtG[(size_t)(f0 + 4) * FIN + k] = (__bf16)w1.x;
    WtG[(size_t)(f0 + 5) * FIN + k] = (__bf16)w1.y;
    WtG[(size_t)(f0 + 6) * FIN + k] = (__bf16)w1.z;
    WtG[(size_t)(f0 + 7) * FIN + k] = (__bf16)w1.w;
}

// ---------- k12: h=in@W (MFMA) -> f_src/f_dst/Mkey + hT (fused) ------------
__global__ __launch_bounds__(64) void k12(const float* __restrict__ in,
                                          const __bf16* __restrict__ WtG,
                                          const float* __restrict__ a,
                                          float* __restrict__ f_src,
                                          float* __restrict__ f_dst,
                                          unsigned* __restrict__ Mkey,
                                          __bf16* __restrict__ hT) {
    __shared__ __bf16 tb[64][16];
    const int lane = threadIdx.x;
    const int m = lane & 15, quad = lane >> 4;
    const int i0 = blockIdx.x * 16;

    f32x4 acc[4];
#pragma unroll
    for (int t = 0; t < 4; ++t) acc[t] = (f32x4){0.f, 0.f, 0.f, 0.f};

    const float* arow = in + (size_t)(i0 + m) * FIN + quad * 8;
    for (int k0 = 0; k0 < FIN; k0 += 32) {
        const float4 x0 = *(const float4*)(arow + k0);
        const float4 x1 = *(const float4*)(arow + k0 + 4);
        bf16x8 af;
        af[0] = (__bf16)x0.x; af[1] = (__bf16)x0.y; af[2] = (__bf16)x0.z; af[3] = (__bf16)x0.w;
        af[4] = (__bf16)x1.x; af[5] = (__bf16)x1.y; af[6] = (__bf16)x1.z; af[7] = (__bf16)x1.w;
#pragma unroll
        for (int t = 0; t < 4; ++t) {
            const bf16x8 bf = *(const bf16x8*)(WtG + (size_t)(t * 16 + m) * FIN + k0 + quad * 8);
            acc[t] = __builtin_amdgcn_mfma_f32_16x16x32_bf16(af, bf, acc[t], 0, 0, 0);
        }
    }
    float s1[4], s2[4];
#pragma unroll
    for (int r = 0; r < 4; ++r) { s1[r] = 0.f; s2[r] = 0.f; }
#pragma unroll
    for (int t = 0; t < 4; ++t) {
        const float a1 = a[t * 16 + m], a2 = a[64 + t * 16 + m];
#pragma unroll
        for (int r = 0; r < 4; ++r) {
            s1[r] += acc[t][r] * a1;
            s2[r] += acc[t][r] * a2;
        }
    }
#pragma unroll
    for (int off = 1; off <= 8; off <<= 1)
#pragma unroll
        for (int r = 0; r < 4; ++r) {
            s1[r] += __shfl_xor(s1[r], off);
            s2[r] += __shfl_xor(s2[r], off);
        }
    float lm = -1e30f;
    if (m == 0) {
#pragma unroll
        for (int r = 0; r < 4; ++r) {
            f_src[i0 + quad * 4 + r] = s1[r];
            f_dst[i0 + quad * 4 + r] = s2[r];
            lm = fmaxf(lm, s2[r]);
        }
    }
    lm = fmaxf(lm, __shfl_xor(lm, 16));
    lm = fmaxf(lm, __shfl_xor(lm, 32));
    if (lane == 0) atomicMax(Mkey, enc_f(lm));

#pragma unroll
    for (int t = 0; t < 4; ++t)
#pragma unroll
        for (int r = 0; r < 4; ++r) tb[t * 16 + m][quad * 4 + r] = (__bf16)acc[t][r];
    __syncthreads();
    {
        const int f = lane;
        const bf16x8 v0 = *(const bf16x8*)&tb[f][0];
        const bf16x8 v1 = *(const bf16x8*)&tb[f][8];
        *(bf16x8*)(hT + (size_t)f * N + i0) = v0;
        *(bf16x8*)(hT + (size_t)f * N + i0 + 8) = v1;
    }
}

// ---------- k3: fused mask+softmax-weight+PV -------------------------------
// No LDS, no barriers. 4 independent waves/block (16 rows each), j split 8-way.
// Rolling register prefetch of the next 64-j adj/f_dst batch keeps ~4KB/wave
// of HBM loads in flight; hT (1MB) and f_dst (32KB) are served from L2/L1.
__global__ __launch_bounds__(256) void k3_attn(const int* __restrict__ adj,
                                               const float* __restrict__ f_src,
                                               const float* __restrict__ fdstG,
                                               const unsigned* __restrict__ Mkey,
                                               const __bf16* __restrict__ hT,
                                               float* __restrict__ num,
                                               float* __restrict__ lsum) {
    const int tid = threadIdx.x;
    const int wv = tid >> 6, lane = tid & 63;
    const int m = lane & 15, quad = lane >> 4;
    const int i0 = (blockIdx.x * 4 + wv) * 16;
    const int jc = blockIdx.y * 1024;
    const float LOG2E = 1.44269504088896f;

    const float M = dec_f(*Mkey);
    const float fs = f_src[i0 + m];
    const float t0 = fs + M;
    const float shift = fmaxf(t0, ALPHA * t0);  // leaky(fs + max f_dst)

    f32x4 acc[4];
#pragma unroll
    for (int t = 0; t < 4; ++t) acc[t] = (f32x4){0.f, 0.f, 0.f, 0.f};
    f32x4 accl = (f32x4){0.f, 0.f, 0.f, 0.f};

    bf16x8 bones;  // ones-column B: row-sums for the denominator
#pragma unroll
    for (int jj = 0; jj < 8; ++jj) bones[jj] = (__bf16)(m == 0 ? 1.0f : 0.0f);

    const int* arow = adj + (size_t)(i0 + m) * N;

    i32x4 A[4];
    f32x4 D[4];
#define LOADJ(Adst, Ddst, J0)                                                   \
    {                                                                           \
        const int* p = arow + (J0) + quad * 8;                                  \
        Adst[0] = __builtin_nontemporal_load((const i32x4*)p);                  \
        Adst[1] = __builtin_nontemporal_load((const i32x4*)(p + 4));            \
        Adst[2] = __builtin_nontemporal_load((const i32x4*)(p + 32));           \
        Adst[3] = __builtin_nontemporal_load((const i32x4*)(p + 36));           \
        const float* q = fdstG + (J0) + quad * 8;                               \
        Ddst[0] = *(const f32x4*)q;                                             \
        Ddst[1] = *(const f32x4*)(q + 4);                                       \
        Ddst[2] = *(const f32x4*)(q + 32);                                      \
        Ddst[3] = *(const f32x4*)(q + 36);                                      \
    }

    LOADJ(A, D, jc)

    for (int j0 = jc; j0 < jc + 1024; j0 += 64) {
        const int jn = (j0 + 64 < jc + 1024) ? j0 + 64 : j0;  // clamp last iter
        i32x4 Bn[4];
        f32x4 En[4];
        LOADJ(Bn, En, jn)

#pragma unroll
        for (int u = 0; u < 2; ++u) {
            const i32x4 Aa = A[u * 2], Ab = A[u * 2 + 1];
            const f32x4 Da = D[u * 2], Db = D[u * 2 + 1];
            float wvv[8];
#pragma unroll
            for (int jj = 0; jj < 8; ++jj) {
                const float fd = jj < 4 ? Da[jj] : Db[jj - 4];
                const int am = jj < 4 ? Aa[jj] : Ab[jj - 4];
                float e = fs + fd;
                e = fmaxf(e, ALPHA * e);
                const float ex = __builtin_amdgcn_exp2f((e - shift) * LOG2E);
                wvv[jj] = am > 0 ? ex : 0.f;
            }
            bf16x8 af;
#pragma unroll
            for (int jj = 0; jj < 8; ++jj) af[jj] = (__bf16)wvv[jj];
#pragma unroll
            for (int t = 0; t < 4; ++t) {
                const bf16x8 bfr =
                    *(const bf16x8*)(hT + (size_t)(t * 16 + m) * N + j0 + u * 32 + quad * 8);
                acc[t] = __builtin_amdgcn_mfma_f32_16x16x32_bf16(af, bfr, acc[t], 0, 0, 0);
            }
            accl = __builtin_amdgcn_mfma_f32_16x16x32_bf16(af, bones, accl, 0, 0, 0);
        }
#pragma unroll
        for (int x = 0; x < 4; ++x) { A[x] = Bn[x]; D[x] = En[x]; }
    }
#undef LOADJ

    // epilogue: C/D col=lane&15, row=quad*4+reg
#pragma unroll
    for (int t = 0; t < 4; ++t)
#pragma unroll
        for (int r = 0; r < 4; ++r)
            atomicAdd(&num[(size_t)(i0 + quad * 4 + r) * FOUT + t * 16 + m], acc[t][r]);
    if (m == 0) {
#pragma unroll
        for (int r = 0; r < 4; ++r) atomicAdd(&lsum[i0 + quad * 4 + r], accl[r]);
    }
}

// ---------- k4: out = leaky(num / lsum, 0.01) ------------------------------
__global__ __launch_bounds__(256) void k4_norm(float* __restrict__ out,
                                               const float* __restrict__ lsum) {
    const int idx = blockIdx.x * 256 + threadIdx.x;
    const float l = lsum[idx >> 6];
    const float v = out[idx] / (l > 0.f ? l : 1.f);
    out[idx] = v > 0.f ? v : 0.01f * v;
}

extern "C" void kernel_launch(void* const* d_in, const int* in_sizes, int n_in,
                              void* d_out, int out_size, void* d_ws, size_t ws_size,
                              hipStream_t stream) {
    const float* in = (const float*)d_in[0];
    const int* adj = (const int*)d_in[1];
    const float* W = (const float*)d_in[2];
    const float* a = (const float*)d_in[3];
    float* out = (float*)d_out;

    char* ws = (char*)d_ws;
    unsigned* Mkey = (unsigned*)ws;
    float* lsum = (float*)(ws + 64);
    float* f_src = (float*)(ws + 32832);
    float* f_dst = (float*)(ws + 65600);
    __bf16* WtG = (__bf16*)(ws + 98368);
    __bf16* hT = (__bf16*)(ws + 163904);

    hipMemsetAsync(ws, 0, 64 + N * 4, stream);                           // Mkey + lsum
    hipMemsetAsync(d_out, 0, (size_t)N * FOUT * sizeof(float), stream);  // num

    k_wt<<<64, 64, 0, stream>>>(W, WtG);
    k12<<<N / 16, 64, 0, stream>>>(in, WtG, a, f_src, f_dst, Mkey, hT);

    dim3 g3(N / 64, 8);
    k3_attn<<<g3, 256, 0, stream>>>(adj, f_src, f_dst, Mkey, hT, out, lsum);
    k4_norm<<<(N * FOUT) / 256, 256, 0, stream>>>(out, lsum);
}

// Round 4
// 427.957 us; speedup vs baseline: 1.0627x; 1.0627x over previous
//
#include <hip/hip_runtime.h>
#include <hip/hip_bf16.h>

#define N 8192
#define FIN 512
#define FOUT 64
#define ALPHA 0.2f

typedef __bf16 bf16x8 __attribute__((ext_vector_type(8)));
typedef float f32x4 __attribute__((ext_vector_type(4)));
typedef int i32x4 __attribute__((ext_vector_type(4)));

constexpr int JC = 512;       // j-chunk per block
constexpr int NCH = N / JC;   // 16 chunks
constexpr int STR = JC + 8;   // LDS row stride (elems); 520*2B keeps 16B align

// ---- workspace layout (bytes) ----
// 0        : Mkey (ordered-uint global max of f_dst; 64B, memset 0)
// 4096     : f_src (32 KB)
// 36864    : f_dst (32 KB)
// 69632    : WtG (bf16 [FOUT][FIN], 64 KB)
// 135168   : hT  (bf16 [FOUT][N], 1 MB)
// 2097152  : plsum (NCH x N f32, 512 KB)
// 4194304  : pnum  (NCH x N x FOUT f32, 32 MB)

__device__ __forceinline__ unsigned enc_f(float x) {
    unsigned u = __float_as_uint(x);
    return (u & 0x80000000u) ? ~u : (u | 0x80000000u);
}
__device__ __forceinline__ float dec_f(unsigned u) {
    return (u & 0x80000000u) ? __uint_as_float(u & 0x7FFFFFFFu) : __uint_as_float(~u);
}

// ---------- k_wt: WtG[f][k] = bf16(W[k][f]) --------------------------------
__global__ __launch_bounds__(64) void k_wt(const float* __restrict__ W,
                                           __bf16* __restrict__ WtG) {
    const int g = blockIdx.x * 64 + threadIdx.x;  // 0..4095
    const int k = g >> 3;
    const int f0 = (g & 7) * 8;
    const float4 w0 = *(const float4*)(W + (size_t)k * FOUT + f0);
    const float4 w1 = *(const float4*)(W + (size_t)k * FOUT + f0 + 4);
    WtG[(size_t)(f0 + 0) * FIN + k] = (__bf16)w0.x;
    WtG[(size_t)(f0 + 1) * FIN + k] = (__bf16)w0.y;
    WtG[(size_t)(f0 + 2) * FIN + k] = (__bf16)w0.z;
    WtG[(size_t)(f0 + 3) * FIN + k] = (__bf16)w0.w;
    WtG[(size_t)(f0 + 4) * FIN + k] = (__bf16)w1.x;
    WtG[(size_t)(f0 + 5) * FIN + k] = (__bf16)w1.y;
    WtG[(size_t)(f0 + 6) * FIN + k] = (__bf16)w1.z;
    WtG[(size_t)(f0 + 7) * FIN + k] = (__bf16)w1.w;
}

// ---------- k12: h=in@W (MFMA) -> f_src/f_dst/Mkey + hT (fused) ------------
__global__ __launch_bounds__(64) void k12(const float* __restrict__ in,
                                          const __bf16* __restrict__ WtG,
                                          const float* __restrict__ a,
                                          float* __restrict__ f_src,
                                          float* __restrict__ f_dst,
                                          unsigned* __restrict__ Mkey,
                                          __bf16* __restrict__ hT) {
    __shared__ __bf16 tb[64][16];
    const int lane = threadIdx.x;
    const int m = lane & 15, quad = lane >> 4;
    const int i0 = blockIdx.x * 16;

    f32x4 acc[4];
#pragma unroll
    for (int t = 0; t < 4; ++t) acc[t] = (f32x4){0.f, 0.f, 0.f, 0.f};

    const float* arow = in + (size_t)(i0 + m) * FIN + quad * 8;
    for (int k0 = 0; k0 < FIN; k0 += 32) {
        const float4 x0 = *(const float4*)(arow + k0);
        const float4 x1 = *(const float4*)(arow + k0 + 4);
        bf16x8 af;
        af[0] = (__bf16)x0.x; af[1] = (__bf16)x0.y; af[2] = (__bf16)x0.z; af[3] = (__bf16)x0.w;
        af[4] = (__bf16)x1.x; af[5] = (__bf16)x1.y; af[6] = (__bf16)x1.z; af[7] = (__bf16)x1.w;
#pragma unroll
        for (int t = 0; t < 4; ++t) {
            const bf16x8 bf = *(const bf16x8*)(WtG + (size_t)(t * 16 + m) * FIN + k0 + quad * 8);
            acc[t] = __builtin_amdgcn_mfma_f32_16x16x32_bf16(af, bf, acc[t], 0, 0, 0);
        }
    }
    float s1[4], s2[4];
#pragma unroll
    for (int r = 0; r < 4; ++r) { s1[r] = 0.f; s2[r] = 0.f; }
#pragma unroll
    for (int t = 0; t < 4; ++t) {
        const float a1 = a[t * 16 + m], a2 = a[64 + t * 16 + m];
#pragma unroll
        for (int r = 0; r < 4; ++r) {
            s1[r] += acc[t][r] * a1;
            s2[r] += acc[t][r] * a2;
        }
    }
#pragma unroll
    for (int off = 1; off <= 8; off <<= 1)
#pragma unroll
        for (int r = 0; r < 4; ++r) {
            s1[r] += __shfl_xor(s1[r], off);
            s2[r] += __shfl_xor(s2[r], off);
        }
    float lm = -1e30f;
    if (m == 0) {
#pragma unroll
        for (int r = 0; r < 4; ++r) {
            f_src[i0 + quad * 4 + r] = s1[r];
            f_dst[i0 + quad * 4 + r] = s2[r];
            lm = fmaxf(lm, s2[r]);
        }
    }
    lm = fmaxf(lm, __shfl_xor(lm, 16));
    lm = fmaxf(lm, __shfl_xor(lm, 32));
    if (lane == 0) atomicMax(Mkey, enc_f(lm));

#pragma unroll
    for (int t = 0; t < 4; ++t)
#pragma unroll
        for (int r = 0; r < 4; ++r) tb[t * 16 + m][quad * 4 + r] = (__bf16)acc[t][r];
    __syncthreads();
    {
        const int f = lane;
        const bf16x8 v0 = *(const bf16x8*)&tb[f][0];
        const bf16x8 v1 = *(const bf16x8*)&tb[f][8];
        *(bf16x8*)(hT + (size_t)f * N + i0) = v0;
        *(bf16x8*)(hT + (size_t)f * N + i0 + 8) = v1;
    }
}

// ---------- k3: fused mask+softmax-weight+PV -------------------------------
// Block = 64 rows x 512-j chunk. hT tile + f_dst staged to LDS once (single
// barrier), so all LDS consumption is lgkmcnt. adj is the ONLY vmcnt stream,
// software-pipelined 3 deep (waits are vmcnt(8), never a drain). Partial
// sums stored disjointly (no atomics), reduced in k4.
__global__ __launch_bounds__(256) void k3_attn(const int* __restrict__ adj,
                                               const float* __restrict__ f_src,
                                               const float* __restrict__ fdstG,
                                               const unsigned* __restrict__ Mkey,
                                               const __bf16* __restrict__ hT,
                                               float* __restrict__ pnum,
                                               float* __restrict__ plsum) {
    __shared__ __bf16 sh[64 * STR];  // 66,560 B
    __shared__ float sfd[JC];        // 2 KB
    const int tid = threadIdx.x;
    const int wv = tid >> 6, lane = tid & 63;
    const int m = lane & 15, quad = lane >> 4;
    const int i0 = (blockIdx.x * 4 + wv) * 16;
    const int jc = blockIdx.y * JC;
    const float LOG2E = 1.44269504088896f;

    // ---- stage hT[:, jc:jc+512] (64 KB) + f_dst chunk, one barrier ----
#pragma unroll
    for (int c = tid; c < 64 * JC / 8; c += 256) {
        const int f = c >> 6, off = (c & 63) * 8;
        *(bf16x8*)&sh[f * STR + off] = *(const bf16x8*)(hT + (size_t)f * N + jc + off);
    }
    if (tid < JC / 4) *(f32x4*)&sfd[tid * 4] = *(const f32x4*)(fdstG + jc + tid * 4);
    __syncthreads();

    const float M = dec_f(*Mkey);
    const float fs = f_src[i0 + m];
    const float t0 = fs + M;
    const float shift = fmaxf(t0, ALPHA * t0);  // leaky(fs + max f_dst)

    f32x4 acc[4];
#pragma unroll
    for (int t = 0; t < 4; ++t) acc[t] = (f32x4){0.f, 0.f, 0.f, 0.f};
    f32x4 accl = (f32x4){0.f, 0.f, 0.f, 0.f};

    bf16x8 bones;  // ones-column B: row-sums -> denominator
#pragma unroll
    for (int jj = 0; jj < 8; ++jj) bones[jj] = (__bf16)(m == 0 ? 1.0f : 0.0f);

    const int* arow = adj + (size_t)(i0 + m) * N + jc;

    i32x4 buf[3][4];
#pragma unroll
    for (int p = 0; p < 3; ++p) {
        const int* q = arow + p * 64 + quad * 8;
        buf[p][0] = __builtin_nontemporal_load((const i32x4*)q);
        buf[p][1] = __builtin_nontemporal_load((const i32x4*)(q + 4));
        buf[p][2] = __builtin_nontemporal_load((const i32x4*)(q + 32));
        buf[p][3] = __builtin_nontemporal_load((const i32x4*)(q + 36));
    }

#pragma unroll
    for (int it = 0; it < 8; ++it) {
        i32x4 cur[4];
#pragma unroll
        for (int x = 0; x < 4; ++x) cur[x] = buf[it % 3][x];
        if (it + 3 < 8) {
            const int* q = arow + (it + 3) * 64 + quad * 8;
            buf[it % 3][0] = __builtin_nontemporal_load((const i32x4*)q);
            buf[it % 3][1] = __builtin_nontemporal_load((const i32x4*)(q + 4));
            buf[it % 3][2] = __builtin_nontemporal_load((const i32x4*)(q + 32));
            buf[it % 3][3] = __builtin_nontemporal_load((const i32x4*)(q + 36));
        }
        const int jloc = it * 64;
#pragma unroll
        for (int u = 0; u < 2; ++u) {
            const i32x4 Aa = cur[u * 2], Ab = cur[u * 2 + 1];
            const f32x4 Da = *(const f32x4*)&sfd[jloc + u * 32 + quad * 8];
            const f32x4 Db = *(const f32x4*)&sfd[jloc + u * 32 + quad * 8 + 4];
            float wvv[8];
#pragma unroll
            for (int jj = 0; jj < 8; ++jj) {
                const float fd = jj < 4 ? Da[jj] : Db[jj - 4];
                const int am = jj < 4 ? Aa[jj] : Ab[jj - 4];
                float e = fs + fd;
                e = fmaxf(e, ALPHA * e);
                const float ex = __builtin_amdgcn_exp2f((e - shift) * LOG2E);
                wvv[jj] = am > 0 ? ex : 0.f;
            }
            bf16x8 af;
#pragma unroll
            for (int jj = 0; jj < 8; ++jj) af[jj] = (__bf16)wvv[jj];
#pragma unroll
            for (int t = 0; t < 4; ++t) {
                const bf16x8 bfr =
                    *(const bf16x8*)&sh[(t * 16 + m) * STR + jloc + u * 32 + quad * 8];
                acc[t] = __builtin_amdgcn_mfma_f32_16x16x32_bf16(af, bfr, acc[t], 0, 0, 0);
            }
            accl = __builtin_amdgcn_mfma_f32_16x16x32_bf16(af, bones, accl, 0, 0, 0);
        }
    }

    // disjoint partial-sum stores (C/D: col=lane&15, row=quad*4+reg)
    float* pn = pnum + (size_t)blockIdx.y * N * FOUT;
#pragma unroll
    for (int t = 0; t < 4; ++t)
#pragma unroll
        for (int r = 0; r < 4; ++r)
            pn[(size_t)(i0 + quad * 4 + r) * FOUT + t * 16 + m] = acc[t][r];
    if (m == 0) {
#pragma unroll
        for (int r = 0; r < 4; ++r)
            plsum[(size_t)blockIdx.y * N + i0 + quad * 4 + r] = accl[r];
    }
}

// ---------- k4: reduce partials, out = leaky(num/lsum, 0.01) ---------------
__global__ __launch_bounds__(256) void k4_norm(const float* __restrict__ pnum,
                                               const float* __restrict__ plsum,
                                               float* __restrict__ out) {
    const int idx = blockIdx.x * 256 + threadIdx.x;  // over N*FOUT
    const int row = idx >> 6;
    float s = 0.f, l = 0.f;
#pragma unroll
    for (int c = 0; c < NCH; ++c) {
        s += pnum[(size_t)c * N * FOUT + idx];
        l += plsum[(size_t)c * N + row];
    }
    const float v = s / (l > 0.f ? l : 1.f);
    out[idx] = v > 0.f ? v : 0.01f * v;
}

extern "C" void kernel_launch(void* const* d_in, const int* in_sizes, int n_in,
                              void* d_out, int out_size, void* d_ws, size_t ws_size,
                              hipStream_t stream) {
    const float* in = (const float*)d_in[0];
    const int* adj = (const int*)d_in[1];
    const float* W = (const float*)d_in[2];
    const float* a = (const float*)d_in[3];
    float* out = (float*)d_out;

    char* ws = (char*)d_ws;
    unsigned* Mkey = (unsigned*)ws;
    float* f_src = (float*)(ws + 4096);
    float* f_dst = (float*)(ws + 36864);
    __bf16* WtG = (__bf16*)(ws + 69632);
    __bf16* hT = (__bf16*)(ws + 135168);
    float* plsum = (float*)(ws + 2097152);
    float* pnum = (float*)(ws + 4194304);

    hipMemsetAsync(ws, 0, 64, stream);  // Mkey only

    k_wt<<<64, 64, 0, stream>>>(W, WtG);
    k12<<<N / 16, 64, 0, stream>>>(in, WtG, a, f_src, f_dst, Mkey, hT);

    dim3 g3(N / 64, NCH);
    k3_attn<<<g3, 256, 0, stream>>>(adj, f_src, f_dst, Mkey, hT, pnum, plsum);
    k4_norm<<<(N * FOUT) / 256, 256, 0, stream>>>(pnum, plsum, out);
}